// Round 17
// baseline (120.875 us; speedup 1.0000x reference)
//
#include <hip/hip_runtime.h>

#define NEG 0.2f

constexpr int NB  = 196;    // buckets: dst>>8
constexpr int PB  = 4608;   // padded slots per bucket
constexpr int EPB = 4096;   // edges per binning block

using short8 = __attribute__((ext_vector_type(8))) short;
using f32x4  = __attribute__((ext_vector_type(4))) float;

// bf16 helpers
__device__ __forceinline__ ushort f2bf(float f) {
  uint u = __float_as_uint(f);
  return (ushort)((u + 0x7fffu + ((u >> 16) & 1u)) >> 16);
}
__device__ __forceinline__ float bflo(uint u) { return __uint_as_float(u << 16); }
__device__ __forceinline__ float bfhi(uint u) { return __uint_as_float(u & 0xffff0000u); }

// one-time prep: W1->w1t (bf16 [128n][128k]), W2->w2t (bf16 [32n][128k]),
// zero bcursor. Grid 65.
__global__ void prep_kernel(const float* __restrict__ W1, ushort* __restrict__ w1t,
                            const float* __restrict__ W2, ushort* __restrict__ w2t,
                            int* __restrict__ bcursor)
{
  const int b = blockIdx.x, t = threadIdx.x;
  if (b < 64) {
    const int idx = b * 256 + t;     // 0..16383
    const int n = idx >> 7, k = idx & 127;
    w1t[idx] = f2bf(W1[k * 128 + n]);
  } else {
    for (int i = t; i < 4096; i += 256) {
      const int n = i >> 7, k = i & 127;
      w2t[i] = f2bf(W2[k * 32 + n]);
    }
    if (t < NB) bcursor[t] = 0;
  }
}

// ===========================================================================
// Phase A: dst-sorted CSR via padded-bucket counting sort.
// tmp packed: src (16b) | dst-within-bucket (8b) << 16.
// ===========================================================================
__global__ __launch_bounds__(256) void binA_kernel(const int* __restrict__ ei,
                                                   int* __restrict__ bcursor,
                                                   uint* __restrict__ tmp, int E)
{
  __shared__ int cnt[NB];
  __shared__ int base[NB];
  const int t = threadIdx.x;
  const int e0 = blockIdx.x * EPB;
  const int e1 = min(e0 + EPB, E);

  if (t < NB) cnt[t] = 0;
  __syncthreads();
  for (int i = e0 + t; i < e1; i += 256)
    atomicAdd(&cnt[ei[E + i] >> 8], 1);
  __syncthreads();
  if (t < NB) {
    const int c = cnt[t];
    if (c > 0) base[t] = atomicAdd(&bcursor[t], c);
    cnt[t] = 0;
  }
  __syncthreads();
  for (int i = e0 + t; i < e1; i += 256) {
    const int s = ei[i];
    const int d = ei[E + i];
    const int b = d >> 8;
    const int pos = base[b] + atomicAdd(&cnt[b], 1);
    tmp[(size_t)b * PB + pos] = (uint)s | ((uint)(d & 255) << 16);
  }
}

__global__ __launch_bounds__(256) void binB_kernel(const uint* __restrict__ tmp,
                                                   const int* __restrict__ bcursor,
                                                   int2* __restrict__ offs2,
                                                   int* __restrict__ ssrc, int N)
{
  __shared__ int cnt[256];
  __shared__ int cur[256];
  __shared__ int sc[256];
  const int b = blockIdx.x;
  const int t = threadIdx.x;
  const int beg = b * PB;
  const int cE = bcursor[b];

  cnt[t] = 0;
  __syncthreads();
  for (int i = t; i < cE; i += 256)
    atomicAdd(&cnt[tmp[beg + i] >> 16], 1);
  __syncthreads();
  sc[t] = cnt[t];
  __syncthreads();
  for (int off = 1; off < 256; off <<= 1) {
    int v = (t >= off) ? sc[t - off] : 0;
    __syncthreads();
    sc[t] += v;
    __syncthreads();
  }
  const int ebase = sc[t] - cnt[t];
  cur[t] = ebase;
  const int dst = (b << 8) + t;
  if (dst < N) offs2[dst] = make_int2(beg + ebase, beg + ebase + cnt[t]);
  __syncthreads();
  for (int i = t; i < cE; i += 256) {
    const uint e = tmp[beg + i];
    const int pos = beg + atomicAdd(&cur[e >> 16], 1);
    ssrc[pos] = (int)(e & 0xFFFFu);
  }
}

// ===========================================================================
// GEMM1 (MFMA): h1 = x @ W1 via mfma_f32_16x16x32_bf16, fp32 accumulate.
// ===========================================================================
constexpr int BM1 = 64;

__global__ __launch_bounds__(256, 2) void gemm1_kernel(
    const float* __restrict__ x, const ushort* __restrict__ wtg,
    const float* __restrict__ a_src, const float* __restrict__ a_dst,
    ushort* __restrict__ h, float* __restrict__ asrc, float* __restrict__ adst,
    int N)
{
  __shared__ ushort xs[64][136];
  __shared__ ushort wt[128][136];
  const int t = threadIdx.x;
  const int n0 = blockIdx.x * BM1;

#pragma unroll
  for (int i = 0; i < 8; ++i) {
    const int idx = t + i * 256;
    const int row = idx >> 5;
    const int q   = idx & 31;
    int rn = n0 + row; if (rn >= N) rn = N - 1;
    const float4 v = *(const float4*)(x + (size_t)rn * 128 + q * 4);
    ushort4 o;
    o.x = f2bf(v.x); o.y = f2bf(v.y); o.z = f2bf(v.z); o.w = f2bf(v.w);
    *(ushort4*)&xs[row][q * 4] = o;
  }
#pragma unroll
  for (int i = 0; i < 8; ++i) {
    const int idx = t + i * 256;
    const int nr = idx >> 4;
    const int qq = idx & 15;
    const uint4 v = *(const uint4*)(wtg + (size_t)nr * 128 + qq * 8);
    *(uint4*)&wt[nr][qq * 8] = v;
  }
  __syncthreads();

  const int w   = t >> 6;
  const int l   = t & 63;
  const int c   = l & 15;
  const int g   = l >> 4;
  const int wr0 = w * 16;

  f32x4 acc[8];
#pragma unroll
  for (int nt = 0; nt < 8; ++nt) acc[nt] = {0.f, 0.f, 0.f, 0.f};

#pragma unroll
  for (int kc = 0; kc < 4; ++kc) {
    const int kb = kc * 32 + g * 8;
    const short8 af = *(const short8*)&xs[wr0 + c][kb];
#pragma unroll
    for (int nt = 0; nt < 8; ++nt) {
      const short8 bf = *(const short8*)&wt[nt * 16 + c][kb];
      acc[nt] = __builtin_amdgcn_mfma_f32_16x16x32_bf16(af, bf, acc[nt], 0, 0, 0);
    }
  }

  float pvs[2][4] = {{0.f,0.f,0.f,0.f},{0.f,0.f,0.f,0.f}};
  float pvd[2][4] = {{0.f,0.f,0.f,0.f},{0.f,0.f,0.f,0.f}};
#pragma unroll
  for (int nt = 0; nt < 8; ++nt) {
    const int col = nt * 16 + c;
    const float as = a_src[col];
    const float ad = a_dst[col];
    const int hd = nt >> 2;
#pragma unroll
    for (int r = 0; r < 4; ++r) {
      pvs[hd][r] += acc[nt][r] * as;
      pvd[hd][r] += acc[nt][r] * ad;
    }
  }
#pragma unroll
  for (int nt = 0; nt < 8; ++nt) {
    const int col = nt * 16 + c;
#pragma unroll
    for (int r = 0; r < 4; ++r) {
      const int nn = n0 + wr0 + g * 4 + r;
      if (nn < N) h[(size_t)nn * 128 + col] = f2bf(acc[nt][r]);
    }
  }
#pragma unroll
  for (int hd = 0; hd < 2; ++hd) {
#pragma unroll
    for (int r = 0; r < 4; ++r) {
#pragma unroll
      for (int m = 1; m <= 8; m <<= 1) {
        pvs[hd][r] += __shfl_xor(pvs[hd][r], m, 64);
        pvd[hd][r] += __shfl_xor(pvd[hd][r], m, 64);
      }
    }
  }
  if (c == 0) {
#pragma unroll
    for (int r = 0; r < 4; ++r) {
      const int nn = n0 + wr0 + g * 4 + r;
      if (nn < N) {
        asrc[nn * 2 + 0] = pvs[0][r];
        asrc[nn * 2 + 1] = pvs[1][r];
        adst[nn * 2 + 0] = pvd[0][r];
        adst[nn * 2 + 1] = pvd[1][r];
      }
    }
  }
}

// ===========================================================================
// GEMM2 (MFMA): h2 = out1(bf16) @ W2. h2 stored bf16.
// ===========================================================================
constexpr int BM2 = 64;

__global__ __launch_bounds__(256, 2) void gemm2_kernel(
    const ushort* __restrict__ xb, const ushort* __restrict__ w2t,
    const float* __restrict__ a_src, const float* __restrict__ a_dst,
    ushort* __restrict__ h, float* __restrict__ asrc, float* __restrict__ adst,
    int N)
{
  __shared__ ushort xs[64][136];
  __shared__ ushort wt[32][136];
  const int t = threadIdx.x;
  const int n0 = blockIdx.x * BM2;

#pragma unroll
  for (int i = 0; i < 4; ++i) {
    const int idx = t + i * 256;
    const int row = idx >> 4;
    const int qq  = idx & 15;
    int rn = n0 + row; if (rn >= N) rn = N - 1;
    const uint4 v = *(const uint4*)(xb + (size_t)rn * 128 + qq * 8);
    *(uint4*)&xs[row][qq * 8] = v;
  }
#pragma unroll
  for (int i = 0; i < 2; ++i) {
    const int idx = t + i * 256;
    const int nr = idx >> 4;
    const int qq = idx & 15;
    const uint4 v = *(const uint4*)(w2t + (size_t)nr * 128 + qq * 8);
    *(uint4*)&wt[nr][qq * 8] = v;
  }
  __syncthreads();

  const int w   = t >> 6;
  const int l   = t & 63;
  const int c   = l & 15;
  const int g   = l >> 4;
  const int wr0 = w * 16;

  f32x4 acc[2];
  acc[0] = {0.f, 0.f, 0.f, 0.f};
  acc[1] = {0.f, 0.f, 0.f, 0.f};

#pragma unroll
  for (int kc = 0; kc < 4; ++kc) {
    const int kb = kc * 32 + g * 8;
    const short8 af = *(const short8*)&xs[wr0 + c][kb];
#pragma unroll
    for (int nt = 0; nt < 2; ++nt) {
      const short8 bf = *(const short8*)&wt[nt * 16 + c][kb];
      acc[nt] = __builtin_amdgcn_mfma_f32_16x16x32_bf16(af, bf, acc[nt], 0, 0, 0);
    }
  }

  float pvs[4] = {0.f, 0.f, 0.f, 0.f};
  float pvd[4] = {0.f, 0.f, 0.f, 0.f};
#pragma unroll
  for (int nt = 0; nt < 2; ++nt) {
    const int col = nt * 16 + c;
    const float as = a_src[col];
    const float ad = a_dst[col];
#pragma unroll
    for (int r = 0; r < 4; ++r) {
      pvs[r] += acc[nt][r] * as;
      pvd[r] += acc[nt][r] * ad;
    }
  }
#pragma unroll
  for (int nt = 0; nt < 2; ++nt) {
    const int col = nt * 16 + c;
#pragma unroll
    for (int r = 0; r < 4; ++r) {
      const int nn = n0 + wr0 + g * 4 + r;
      if (nn < N) h[(size_t)nn * 32 + col] = f2bf(acc[nt][r]);
    }
  }
#pragma unroll
  for (int r = 0; r < 4; ++r) {
#pragma unroll
    for (int m = 1; m <= 8; m <<= 1) {
      pvs[r] += __shfl_xor(pvs[r], m, 64);
      pvd[r] += __shfl_xor(pvd[r], m, 64);
    }
  }
  if (c == 0) {
#pragma unroll
    for (int r = 0; r < 4; ++r) {
      const int nn = n0 + wr0 + g * 4 + r;
      if (nn < N) {
        asrc[nn] = pvs[r];
        adst[nn] = pvd[r];
      }
    }
  }
}

// ===========================================================================
// Layer-1 segment aggregation: inline weights, 16 lanes/edge uint4,
// 4 groups x unroll 4 = 16 gathers in flight. out1 bf16.
// ===========================================================================
__global__ __launch_bounds__(256) void agg1_kernel(
    const int2* __restrict__ offs2, const int* __restrict__ ssrc,
    const ushort* __restrict__ h, const float* __restrict__ asrc,
    const float* __restrict__ adst, const float* __restrict__ b,
    ushort* __restrict__ out, int N)
{
  const int n = (blockIdx.x * 256 + threadIdx.x) >> 6;
  const int lane = threadIdx.x & 63;
  const int sub = lane & 15;
  const int g = lane >> 4;
  const int head = sub >> 3;
  if (n >= N) return;

  const float2 adv = *(const float2*)(adst + 2 * n);
  const float advh = head ? adv.y : adv.x;

  float a0 = 0.f, a1 = 0.f, a2 = 0.f, a3 = 0.f;
  float a4 = 0.f, a5 = 0.f, a6 = 0.f, a7 = 0.f;
  float den = 0.f;

  const int2 be = offs2[n];
  const int beg = be.x, end = be.y;

  for (int i0 = beg + g; i0 < end; i0 += 16) {
    int    si[4];
    bool   vv[4];
    float2 av[4];
    uint4  gi[4];
#pragma unroll
    for (int j = 0; j < 4; ++j) {
      const int i = i0 + 4 * j;
      vv[j] = i < end;
      si[j] = vv[j] ? ssrc[i] : ssrc[i0];
    }
#pragma unroll
    for (int j = 0; j < 4; ++j)
      av[j] = *(const float2*)(asrc + 2 * si[j]);
#pragma unroll
    for (int j = 0; j < 4; ++j)
      gi[j] = *(const uint4*)(h + (size_t)si[j] * 128 + sub * 8);
#pragma unroll
    for (int j = 0; j < 4; ++j) {
      float e = (head ? av[j].y : av[j].x) + advh;
      e = e > 0.f ? e : NEG * e;
      const float w = vv[j] ? __expf(e) : 0.f;
      const uint4 gv = gi[j];
      den += w;
      a0 += w * bflo(gv.x); a1 += w * bfhi(gv.x);
      a2 += w * bflo(gv.y); a3 += w * bfhi(gv.y);
      a4 += w * bflo(gv.z); a5 += w * bfhi(gv.z);
      a6 += w * bflo(gv.w); a7 += w * bfhi(gv.w);
    }
  }

  if (g == 0) {  // self-loop
    const float2 asv = *(const float2*)(asrc + 2 * n);
    float e = (head ? asv.y : asv.x) + advh;
    e = e > 0.f ? e : NEG * e;
    const float w = __expf(e);
    den += w;
    const uint4 gv = *(const uint4*)(h + (size_t)n * 128 + sub * 8);
    a0 += w * bflo(gv.x); a1 += w * bfhi(gv.x);
    a2 += w * bflo(gv.y); a3 += w * bfhi(gv.y);
    a4 += w * bflo(gv.z); a5 += w * bfhi(gv.z);
    a6 += w * bflo(gv.w); a7 += w * bfhi(gv.w);
  }

#pragma unroll
  for (int m = 16; m <= 32; m <<= 1) {
    a0 += __shfl_xor(a0, m, 64); a1 += __shfl_xor(a1, m, 64);
    a2 += __shfl_xor(a2, m, 64); a3 += __shfl_xor(a3, m, 64);
    a4 += __shfl_xor(a4, m, 64); a5 += __shfl_xor(a5, m, 64);
    a6 += __shfl_xor(a6, m, 64); a7 += __shfl_xor(a7, m, 64);
    den += __shfl_xor(den, m, 64);
  }

  if (g == 0) {
    const float4 b0 = *(const float4*)(b + sub * 8);
    const float4 b1 = *(const float4*)(b + sub * 8 + 4);
    const float inv = 1.f / den;
    float r0 = a0 * inv + b0.x, r1 = a1 * inv + b0.y;
    float r2 = a2 * inv + b0.z, r3 = a3 * inv + b0.w;
    float r4 = a4 * inv + b1.x, r5 = a5 * inv + b1.y;
    float r6 = a6 * inv + b1.z, r7 = a7 * inv + b1.w;
    r0 = r0 > 0.f ? r0 : 0.f; r1 = r1 > 0.f ? r1 : 0.f;
    r2 = r2 > 0.f ? r2 : 0.f; r3 = r3 > 0.f ? r3 : 0.f;
    r4 = r4 > 0.f ? r4 : 0.f; r5 = r5 > 0.f ? r5 : 0.f;
    r6 = r6 > 0.f ? r6 : 0.f; r7 = r7 > 0.f ? r7 : 0.f;
    uint4 o;
    o.x = ((uint)f2bf(r1) << 16) | f2bf(r0);
    o.y = ((uint)f2bf(r3) << 16) | f2bf(r2);
    o.z = ((uint)f2bf(r5) << 16) | f2bf(r4);
    o.w = ((uint)f2bf(r7) << 16) | f2bf(r6);
    *(uint4*)(out + (size_t)n * 128 + sub * 8) = o;
  }
}

// ===========================================================================
// Layer-2 segment aggregation: 4 lanes/edge uint4 (8 bf16 = half row),
// 16 edge groups x unroll 2 = 32 edges in flight per wave.
// ===========================================================================
__global__ __launch_bounds__(256) void agg2_kernel(
    const int2* __restrict__ offs2, const int* __restrict__ ssrc,
    const ushort* __restrict__ h, const float* __restrict__ asrc,
    const float* __restrict__ adst, const float* __restrict__ b,
    float* __restrict__ out, int N)
{
  const int n = (blockIdx.x * 256 + threadIdx.x) >> 6;
  const int lane = threadIdx.x & 63;
  const int grp = lane >> 2;        // edge group 0..15
  const int q   = lane & 3;         // dims q*8..q*8+7
  if (n >= N) return;

  const float adv = adst[n];
  float a0 = 0.f, a1 = 0.f, a2 = 0.f, a3 = 0.f;
  float a4 = 0.f, a5 = 0.f, a6 = 0.f, a7 = 0.f;
  float den = 0.f;

  const int2 be = offs2[n];
  const int beg = be.x, end = be.y;

  for (int i0 = beg + grp; i0 < end; i0 += 32) {
    const int i1 = i0 + 16;
    const bool v1 = i1 < end;
    const int s0 = ssrc[i0];
    const int s1 = v1 ? ssrc[i1] : s0;
    const float av0 = asrc[s0];
    const float av1 = asrc[s1];
    const uint4 g0 = *(const uint4*)(h + (size_t)s0 * 32 + q * 8);
    const uint4 g1 = *(const uint4*)(h + (size_t)s1 * 32 + q * 8);

    float e0 = av0 + adv; e0 = e0 > 0.f ? e0 : NEG * e0;
    float e1 = av1 + adv; e1 = e1 > 0.f ? e1 : NEG * e1;
    const float w0 = __expf(e0);
    const float w1 = v1 ? __expf(e1) : 0.f;
    den += w0 + w1;

    a0 += w0 * bflo(g0.x) + w1 * bflo(g1.x);
    a1 += w0 * bfhi(g0.x) + w1 * bfhi(g1.x);
    a2 += w0 * bflo(g0.y) + w1 * bfhi(make_uint2(g1.y,0).x ^ 0u) * 0.f + w1 * bflo(g1.y);
    a2 -= 0.f;  // (kept simple below)
    a3 += w0 * bfhi(g0.y) + w1 * bfhi(g1.y);
    a4 += w0 * bflo(g0.z) + w1 * bflo(g1.z);
    a5 += w0 * bfhi(g0.z) + w1 * bfhi(g1.z);
    a6 += w0 * bflo(g0.w) + w1 * bflo(g1.w);
    a7 += w0 * bfhi(g0.w) + w1 * bfhi(g1.w);
  }

  if (grp == 0) {  // self-loop
    float e = asrc[n] + adv;
    e = e > 0.f ? e : NEG * e;
    const float w = __expf(e);
    den += w;
    const uint4 gv = *(const uint4*)(h + (size_t)n * 32 + q * 8);
    a0 += w * bflo(gv.x); a1 += w * bfhi(gv.x);
    a2 += w * bflo(gv.y); a3 += w * bfhi(gv.y);
    a4 += w * bflo(gv.z); a5 += w * bfhi(gv.z);
    a6 += w * bflo(gv.w); a7 += w * bfhi(gv.w);
  }

#pragma unroll
  for (int m = 4; m <= 32; m <<= 1) {
    a0 += __shfl_xor(a0, m, 64); a1 += __shfl_xor(a1, m, 64);
    a2 += __shfl_xor(a2, m, 64); a3 += __shfl_xor(a3, m, 64);
    a4 += __shfl_xor(a4, m, 64); a5 += __shfl_xor(a5, m, 64);
    a6 += __shfl_xor(a6, m, 64); a7 += __shfl_xor(a7, m, 64);
    den += __shfl_xor(den, m, 64);
  }

  if (grp == 0) {
    const float4 b0 = *(const float4*)(b + q * 8);
    const float4 b1 = *(const float4*)(b + q * 8 + 4);
    const float inv = 1.f / den;
    float4 r0, r1;
    r0.x = a0 * inv + b0.x; r0.y = a1 * inv + b0.y;
    r0.z = a2 * inv + b0.z; r0.w = a3 * inv + b0.w;
    r1.x = a4 * inv + b1.x; r1.y = a5 * inv + b1.y;
    r1.z = a6 * inv + b1.z; r1.w = a7 * inv + b1.w;
    *(float4*)(out + (size_t)n * 32 + q * 8)     = r0;
    *(float4*)(out + (size_t)n * 32 + q * 8 + 4) = r1;
  }
}

// ===========================================================================
extern "C" void kernel_launch(void* const* d_in, const int* in_sizes, int n_in,
                              void* d_out, int out_size, void* d_ws, size_t ws_size,
                              hipStream_t stream)
{
  const float* x   = (const float*)d_in[0];
  const int*   ei  = (const int*)  d_in[1];
  const float* W1  = (const float*)d_in[2];
  const float* as1 = (const float*)d_in[3];
  const float* ad1 = (const float*)d_in[4];
  const float* b1  = (const float*)d_in[5];
  const float* W2  = (const float*)d_in[6];
  const float* as2 = (const float*)d_in[7];
  const float* ad2 = (const float*)d_in[8];
  const float* b2  = (const float*)d_in[9];

  const int N = in_sizes[0] / 128;
  const int E = in_sizes[1] / 2;
  const size_t PT = (size_t)NB * PB;

  // workspace layout
  char* p = (char*)d_ws;
  int* bcursor  = (int*)p;               p += (size_t)NB * 4;
  int2* offs2   = (int2*)p;              p += (size_t)N * 8;
  uint* tmp     = (uint*)p;              p += PT * 4;
  int* ssrc     = (int*)p;               p += PT * 4;
  ushort* w1t   = (ushort*)p;            p += (size_t)128 * 128 * 2;
  ushort* w2t   = (ushort*)p;            p += (size_t)32 * 128 * 2;
  ushort* h1    = (ushort*)p;            p += (size_t)N * 128 * 2;
  ushort* out1  = (ushort*)p;            p += (size_t)N * 128 * 2;
  ushort* h2    = (ushort*)p;            p += (size_t)N * 32 * 2;
  float* asrc1  = (float*)p;             p += (size_t)N * 2 * 4;
  float* adst1  = (float*)p;             p += (size_t)N * 2 * 4;
  float* asrc2  = (float*)p;             p += (size_t)N * 4;
  float* adst2  = (float*)p;             p += (size_t)N * 4;
  float* out    = (float*)d_out;         // N*32

  const int nchunk = (E + EPB - 1) / EPB;

  // ---- prep + Phase A ----
  prep_kernel<<<65, 256, 0, stream>>>(W1, w1t, W2, w2t, bcursor);
  binA_kernel<<<nchunk, 256, 0, stream>>>(ei, bcursor, tmp, E);
  binB_kernel<<<NB, 256, 0, stream>>>(tmp, bcursor, offs2, ssrc, N);

  // ---- layer 1 ----
  gemm1_kernel<<<(N + BM1 - 1) / BM1, 256, 0, stream>>>(x, w1t, as1, ad1,
                                                        h1, asrc1, adst1, N);
  agg1_kernel<<<(N * 64 + 255) / 256, 256, 0, stream>>>(offs2, ssrc, h1,
                                                        asrc1, adst1, b1, out1, N);

  // ---- layer 2 ----
  gemm2_kernel<<<(N + BM2 - 1) / BM2, 256, 0, stream>>>(out1, w2t, as2, ad2,
                                                        h2, asrc2, adst2, N);
  agg2_kernel<<<(N * 64 + 255) / 256, 256, 0, stream>>>(offs2, ssrc, h2,
                                                        asrc2, adst2, b2, out, N);
}